// Round 5
// baseline (237.493 us; speedup 1.0000x reference)
//
#include <hip/hip_runtime.h>
#include <math.h>

// B=8192, T=1024, WS=5, H=6, IN=15, OUT=2
#define TLEN  1024
#define NSTEP 1019

// DPP sum over each consecutive 8-lane group (result in all 8 lanes).
template <int CTRL>
__device__ __forceinline__ float dpp_add(float v) {
    union { int i; float f; } in, out;
    in.f = v;
    out.i = __builtin_amdgcn_update_dpp(0, in.i, CTRL, 0xF, 0xF, false);
    return v + out.f;
}
__device__ __forceinline__ float sum8(float v) {
    v = dpp_add<0xB1>(v);    // quad_perm xor1
    v = dpp_add<0x4E>(v);    // quad_perm xor2
    v = dpp_add<0x141>(v);   // row_half_mirror = xor4
    return v;
}
// cross-half combine: v + (other 8-lane half of the 16-lane row), row_ror:8
__device__ __forceinline__ float comb16(float v) {
    return dpp_add<0x128>(v);
}

__device__ __forceinline__ float fast_exp2(float z) {
#if __has_builtin(__builtin_amdgcn_exp2f)
    return __builtin_amdgcn_exp2f(z);
#else
    return exp2f(z);
#endif
}

__global__ __launch_bounds__(64) void MLP_or_nextstep_kernel(
    const float* __restrict__ traj,   // (B, T, 3)
    const float* __restrict__ W1,     // (6, 15)
    const float* __restrict__ b1,     // (6,)
    const float* __restrict__ W2,     // (2, 6)
    const float* __restrict__ b2,     // (2,)
    float* __restrict__ out)          // (B, 1019, 2)
{
    __shared__ float lds_u[TLEN][4];  // 16 KB: u for the block's 4 elements, all T

    const int lane = threadIdx.x;
    const int e    = lane >> 4;        // element slot (4 per wave, 16 lanes each)
    const int kk   = (lane >> 3) & 1;  // half: 0 -> {z0,z1}/a-output, 1 -> {z2}/b-output
    const int n    = lane & 7;         // neuron id (0..5 real; 6 carries bias)
    const int bstart = blockIdx.x * 4;
    const int b = bstart + e;

    const float* __restrict__ base = traj + (size_t)b * (TLEN * 3);
    float* outf = out + (size_t)b * (NSTEP * 2);

    // ---- stage ALL u rows: lane i -> elem (i&3), row 16j+(i>>2); dest word 64j+i ----
    {
        const int s_elem = lane & 3;
        const int s_row  = lane >> 2;
        const float* __restrict__ sbase = traj + (size_t)(bstart + s_elem) * (TLEN * 3);
        for (int j = 0; j < TLEN / 16; ++j) {
            const float* gp = sbase + (size_t)(16 * j + s_row) * 3;
            __builtin_amdgcn_global_load_lds(
                (const __attribute__((address_space(1))) void*)gp,
                (__attribute__((address_space(3))) void*)&lds_u[16 * j][0],
                4, 0, 0);
        }
    }

    // ---- per-lane weights, split-K folded ----
    // z = (2*log2e)*preact ; tanh = 1 - 2/(2^z+1) = 1 - 2*r
    // k=0 lane computes z0 (u-dot) + z1 (a-hist dot); k=1 computes z2 (b-hist dot + b1).
    // z = zp + dpp_ror8(zp) == (z0+z1)+z2 (k=0) / z2+(z0+z1) (k=1) -- commutative, bit-same.
    const float KK = 2.8853900817779268f;   // 2*log2(e)
    const int nr = (n < 6) ? n : 5;
    float w1row[15];
#pragma unroll
    for (int j = 0; j < 15; ++j) w1row[j] = KK * W1[nr * 15 + j];
    const float b1r = KK * b1[nr];
    float wu[5], wh[5];
#pragma unroll
    for (int j = 0; j < 5; ++j) {
        wu[j] = kk ? 0.0f : w1row[j];          // u-dot weights (k=0 only)
        wh[j] = kk ? w1row[10 + j] : w1row[5 + j];  // own-half history weights
    }
    const float seed = kk ? b1r : 0.0f;        // z2 starts at b1r; z1 starts at 0
    const float w2_l = (n < 6) ? W2[kk * 6 + n] : 0.0f;
    const float bias = (n == 6) ? b2[kk] : 0.0f;
    const float c1 = -2.0f * w2_l, c0 = w2_l + bias;

    // ---- warmup (one-time; latency-irrelevant) ----
    // h[] = own-half sliding window: starts as v (k=0) / w (k=1) raw inputs,
    // pushes own-half outputs. Identical summand sets & order to reference.
    float h[5];
    float uu[12];
#pragma unroll
    for (int i = 0; i < 12; ++i) uu[i] = base[i * 3];
#pragma unroll
    for (int i = 0; i < 5; ++i) h[i] = base[i * 3 + 1 + kk];

    auto wstep = [&](float x0, float x1, float x2, float x3, float x4) -> float {
        float zh = fmaf(wh[0], h[0], seed);
        zh = fmaf(wh[1], h[1], zh);
        zh = fmaf(wh[2], h[2], zh);
        zh = fmaf(wh[3], h[3], zh);
        zh = fmaf(wh[4], h[4], zh);
        float du = wu[0] * x0;
        du = fmaf(wu[1], x1, du);
        du = fmaf(wu[2], x2, du);
        du = fmaf(wu[3], x3, du);
        du = fmaf(wu[4], x4, du);
        float zp = du + zh;
        float z  = comb16(zp);
        float r  = __builtin_amdgcn_rcpf(fast_exp2(z) + 1.0f);
        float y  = sum8(fmaf(c1, r, c0));
        h[0] = h[1]; h[1] = h[2]; h[2] = h[3]; h[3] = h[4]; h[4] = y;
        return y;
    };

    {
        float pv[5];
        pv[0] = wstep(uu[0], uu[1], uu[2], uu[3], uu[4]);
        pv[1] = wstep(uu[1], uu[2], uu[3], uu[4], uu[5]);
        pv[2] = wstep(uu[2], uu[3], uu[4], uu[6], uu[7]);
        pv[3] = wstep(uu[3], uu[4], uu[7], uu[8], uu[9]);
        pv[4] = wstep(uu[4], uu[8], uu[9], uu[10], uu[11]);
        if (n == 0) {
#pragma unroll
            for (int i = 0; i < 5; ++i) outf[2 * i + kk] = pv[i];
        }
    }

    __syncthreads();   // staging drain, once

    // ---- convoy-breaker: desynchronize SIMD-mate waves' step phases ----
    // Waves sharing a SIMD run identical deterministic code and stay
    // phase-locked -> their chain bubbles coincide and TLP hides nothing
    // (measured: wall = busy + ~155 cyc in ALL multi-wave configs).
    // A one-time dependent-FMA delay of (blockIdx&3)*~56 cyc puts SIMD-mates
    // at different points of the step cycle so one wave's bubbles align with
    // the other's issue bursts. Dead value kept live via asm volatile.
    {
        const int cls = blockIdx.x & 3;
        float d = (float)lane + 1.0f;
        for (int c = 0; c < cls; ++c) {
#pragma unroll
            for (int i = 0; i < 8; ++i) d = fmaf(d, 1.0000001f, 1.0f);
        }
        asm volatile("" :: "v"(d));
    }

    // ---- scan t = 5..1018, software-pipelined, 2 waves/SIMD chip-wide ----
    // h[] now holds {pv0..pv4} (own half).
    const float* up  = &lds_u[5][e];   // u[t0+i] = up[4*i]
    const float* upn;
    float* spf = outf + (n + 5) * 2 + kk;  // lane n stores step-slot n, own component
    float unA[9], unB[9];

#pragma unroll
    for (int i = 0; i < 9; ++i) unA[i] = up[4 * i];
    upn = up + 20;                     // next group to load: t0=10

#define LOADN(BUF)                                                           \
    {                                                                        \
        _Pragma("unroll")                                                    \
        for (int i = 0; i < 9; ++i) BUF[i] = upn[4 * i];                     \
        upn += 20;                                                           \
    }

    // du[i] = z0 chain for step i of a group (k=0 real; k=1 -> +-0, unused)
    float duC[5], duD[5];
#pragma unroll
    for (int i = 0; i < 5; ++i) {
        float d = wu[0] * unA[i];
        d = fmaf(wu[1], unA[i + 1], d);
        d = fmaf(wu[2], unA[i + 2], d);
        d = fmaf(wu[3], unA[i + 3], d);
        d = fmaf(wu[4], unA[i + 4], d);
        duC[i] = d;
    }

    LOADN(unB)                         // t0=10; upn -> 15

    // partial for first step (t=5, S=0): history terms at positions 0..3
    float pC, pN;
    pC = fmaf(wh[0], h[0], seed);
    pC = fmaf(wh[1], h[1], pC);
    pC = fmaf(wh[2], h[2], pC);
    pC = fmaf(wh[3], h[3], pC);

// STEP: finish step S (chain: fma -> add -> comb-dpp -> exp -> add -> rcp ->
// fma -> 3 dpp). Next-step partial + next-group du sit in the exp shadow;
// the desynced co-resident wave on each SIMD fills the remaining stalls.
#define STEP(S, DUC, DUN, UN, J, M)                                          \
    {                                                                        \
        float t_  = fmaf(wh[4], h[((S) + 4) % 5], pC);                       \
        float zp_ = DUC[S] + t_;                                             \
        float z_  = comb16(zp_);                                             \
        float ex_ = fast_exp2(z_);                                           \
        pN = fmaf(wh[0], h[((S) + 1) % 5], seed);                            \
        pN = fmaf(wh[1], h[((S) + 2) % 5], pN);                              \
        pN = fmaf(wh[2], h[((S) + 3) % 5], pN);                              \
        pN = fmaf(wh[3], h[((S) + 4) % 5], pN);                              \
        {                                                                    \
            float d_ = wu[0] * UN[S];                                        \
            d_ = fmaf(wu[1], UN[(S) + 1], d_);                               \
            d_ = fmaf(wu[2], UN[(S) + 2], d_);                               \
            d_ = fmaf(wu[3], UN[(S) + 3], d_);                               \
            d_ = fmaf(wu[4], UN[(S) + 4], d_);                               \
            DUN[S] = d_;                                                     \
        }                                                                    \
        float r_ = __builtin_amdgcn_rcpf(ex_ + 1.0f);                        \
        float y_ = fmaf(c1, r_, c0);                                         \
        y_ = dpp_add<0xB1>(y_);                                              \
        y_ = dpp_add<0x4E>(y_);                                              \
        y_ = dpp_add<0x141>(y_);                                             \
        if (n == (J)) ks##M = y_;                                            \
        h[(S) % 5] = y_;                                                     \
        pC = pN;                                                             \
    }

#define STORE(M) spf[16 * (M)] = ks##M;

    // 25 superblocks x 40 steps: t = 5 .. 1004
    for (int sb = 0; sb < 25; ++sb) {
        float ks0 = 0, ks1 = 0, ks2 = 0, ks3 = 0, ks4 = 0;
        // gg0: compute group A-data (duC), build duD from unB, refill unA
        LOADN(unA)
        STEP(0, duC, duD, unB, 0, 0) STEP(1, duC, duD, unB, 1, 0) STEP(2, duC, duD, unB, 2, 0)
        STEP(3, duC, duD, unB, 3, 0) STEP(4, duC, duD, unB, 4, 0)
        // gg1
        LOADN(unB)
        STEP(0, duD, duC, unA, 5, 0) STEP(1, duD, duC, unA, 6, 0) STEP(2, duD, duC, unA, 7, 0) STORE(0)
        STEP(3, duD, duC, unA, 0, 1) STEP(4, duD, duC, unA, 1, 1)
        // gg2
        LOADN(unA)
        STEP(0, duC, duD, unB, 2, 1) STEP(1, duC, duD, unB, 3, 1) STEP(2, duC, duD, unB, 4, 1)
        STEP(3, duC, duD, unB, 5, 1) STEP(4, duC, duD, unB, 6, 1)
        // gg3
        LOADN(unB)
        STEP(0, duD, duC, unA, 7, 1) STORE(1)
        STEP(1, duD, duC, unA, 0, 2) STEP(2, duD, duC, unA, 1, 2) STEP(3, duD, duC, unA, 2, 2) STEP(4, duD, duC, unA, 3, 2)
        // gg4
        LOADN(unA)
        STEP(0, duC, duD, unB, 4, 2) STEP(1, duC, duD, unB, 5, 2) STEP(2, duC, duD, unB, 6, 2)
        STEP(3, duC, duD, unB, 7, 2) STORE(2)
        STEP(4, duC, duD, unB, 0, 3)
        // gg5
        LOADN(unB)
        STEP(0, duD, duC, unA, 1, 3) STEP(1, duD, duC, unA, 2, 3) STEP(2, duD, duC, unA, 3, 3)
        STEP(3, duD, duC, unA, 4, 3) STEP(4, duD, duC, unA, 5, 3)
        // gg6
        LOADN(unA)
        STEP(0, duC, duD, unB, 6, 3) STEP(1, duC, duD, unB, 7, 3) STORE(3)
        STEP(2, duC, duD, unB, 0, 4) STEP(3, duC, duD, unB, 1, 4) STEP(4, duC, duD, unB, 2, 4)
        // gg7
        LOADN(unB)
        STEP(0, duD, duC, unA, 3, 4) STEP(1, duD, duC, unA, 4, 4) STEP(2, duD, duC, unA, 5, 4)
        STEP(3, duD, duC, unA, 6, 4) STEP(4, duD, duC, unA, 7, 4) STORE(4)

        spf += 80;
    }

    // ---- tail: t = 1005..1018 (14 steps), per-step stores from n==0 lanes ----
    // state: unA holds rows 1005..1013, unB holds 1010..1018, upn -> 1015
    float* tpf = outf + 1005 * 2 + kk;
#define TSTEP(S, UN, K)                                                      \
    {                                                                        \
        float zh_ = fmaf(wh[0], h[(S) % 5], seed);                           \
        zh_ = fmaf(wh[1], h[((S) + 1) % 5], zh_);                            \
        zh_ = fmaf(wh[2], h[((S) + 2) % 5], zh_);                            \
        zh_ = fmaf(wh[3], h[((S) + 3) % 5], zh_);                            \
        zh_ = fmaf(wh[4], h[((S) + 4) % 5], zh_);                            \
        float d_ = wu[0] * UN[S];                                            \
        d_ = fmaf(wu[1], UN[(S) + 1], d_);                                   \
        d_ = fmaf(wu[2], UN[(S) + 2], d_);                                   \
        d_ = fmaf(wu[3], UN[(S) + 3], d_);                                   \
        d_ = fmaf(wu[4], UN[(S) + 4], d_);                                   \
        float zp_ = d_ + zh_;                                                \
        float z_  = comb16(zp_);                                             \
        float r_ = __builtin_amdgcn_rcpf(fast_exp2(z_) + 1.0f);              \
        float y_ = sum8(fmaf(c1, r_, c0));                                   \
        if (n == 0) tpf[2 * (K)] = y_;                                       \
        h[(S) % 5] = y_;                                                     \
    }

    TSTEP(0, unA, 0) TSTEP(1, unA, 1) TSTEP(2, unA, 2) TSTEP(3, unA, 3) TSTEP(4, unA, 4)
    LOADN(unA)   // t0=1015, rows 1015..1023 (in bounds)
    TSTEP(0, unB, 5) TSTEP(1, unB, 6) TSTEP(2, unB, 7) TSTEP(3, unB, 8) TSTEP(4, unB, 9)
    TSTEP(0, unA, 10) TSTEP(1, unA, 11) TSTEP(2, unA, 12) TSTEP(3, unA, 13)

#undef TSTEP
#undef STORE
#undef STEP
#undef LOADN
}

extern "C" void kernel_launch(void* const* d_in, const int* in_sizes, int n_in,
                              void* d_out, int out_size, void* d_ws, size_t ws_size,
                              hipStream_t stream) {
    const float* traj = (const float*)d_in[0];
    const float* W1   = (const float*)d_in[1];
    const float* b1   = (const float*)d_in[2];
    const float* W2   = (const float*)d_in[3];
    const float* b2   = (const float*)d_in[4];
    float* out = (float*)d_out;

    // 16 lanes/element (split-K halves), 4 elements/wave
    // -> 2048 single-wave blocks = 2 waves/SIMD chip-wide (the TLP that hides the chain)
    const int grid = 8192 / 4;
    MLP_or_nextstep_kernel<<<grid, 64, 0, stream>>>(traj, W1, b1, W2, b2, out);
}